// Round 1
// baseline (109.813 us; speedup 1.0000x reference)
//
#include <hip/hip_runtime.h>
#include <hip/hip_bf16.h>
#include <math.h>

#define NN   8192
#define FIN  256
#define HID  64
#define NH   4
#define NC   16
#define MAXD 128
#define ALPHA 0.2f

// ---------------------------------------------------------------------------
// Kernel A: fused {adjacency scan -> CSR} + {fts1 = x @ W1 per head, f1/f2}.
// Blocks [0,512): GEMM (128 row-tiles x 4 heads). Blocks [512,2560): scan
// (4 rows/block, one wave per row). GEMM first so it overlaps the BW-bound scan.
// ---------------------------------------------------------------------------
__global__ __launch_bounds__(256) void k_scan_gemm(
    const float* __restrict__ bias, const float* __restrict__ seq,
    const float* __restrict__ W1, const float* __restrict__ a1s,
    const float* __restrict__ a1d, const float* __restrict__ b1s,
    const float* __restrict__ b1d,
    int* __restrict__ deg, int* __restrict__ cols,
    float* __restrict__ fts1, float* __restrict__ f1v, float* __restrict__ f2v)
{
    __shared__ float xs[64][68];           // 64 rows x 64 k, pad to 68 (16B-aligned rows)
    __shared__ union {
        float w[64][68];                   // 64 k x 64 d
        struct { float r1[64][17]; float r2[64][17]; } red;
    } U;

    const int bid = blockIdx.x;
    const int t   = threadIdx.x;

    if (bid >= 512) {
        // ---------------- adjacency scan: edge iff bias[i][j] == 0.0f ----------
        const int wv = t >> 6, lane = t & 63;
        const int row = (bid - 512) * 4 + wv;
        const float4* rp = (const float4*)(bias + (size_t)row * NN);
        int* crow = cols + (size_t)row * MAXD;
        const unsigned long long lt = (1ull << lane) - 1ull;
        int base = 0;
        for (int mit = 0; mit < 8; ++mit) {
            // 4 outstanding 1KB wave-loads to keep HBM busy
            float4 vv[4];
            #pragma unroll
            for (int q = 0; q < 4; ++q) vv[q] = rp[mit*256 + q*64 + lane];
            #pragma unroll
            for (int q = 0; q < 4; ++q) {
                const float4 v = vv[q];
                const unsigned long long m0 = __ballot(v.x == 0.f);
                const unsigned long long m1 = __ballot(v.y == 0.f);
                const unsigned long long m2 = __ballot(v.z == 0.f);
                const unsigned long long m3 = __ballot(v.w == 0.f);
                int p = base + __popcll(m0&lt) + __popcll(m1&lt)
                             + __popcll(m2&lt) + __popcll(m3&lt);
                const int colbase = mit*1024 + q*256 + lane*4;
                if (v.x == 0.f) { if (p < MAXD) crow[p] = colbase;     ++p; }
                if (v.y == 0.f) { if (p < MAXD) crow[p] = colbase + 1; ++p; }
                if (v.z == 0.f) { if (p < MAXD) crow[p] = colbase + 2; ++p; }
                if (v.w == 0.f) { if (p < MAXD) crow[p] = colbase + 3; ++p; }
                base += __popcll(m0) + __popcll(m1) + __popcll(m2) + __popcll(m3);
            }
        }
        if (lane == 0) deg[row] = base < MAXD ? base : MAXD;
        return;
    }

    // ---------------- fts1 GEMM: [64 nodes] x [256 k] x [64 d], one head ------
    const int head    = bid & 3;
    const int rowbase = (bid >> 2) * 64;
    const int tr = t >> 4, tc = t & 15;

    float acc[4][4] = {};
    for (int kc = 0; kc < 4; ++kc) {
        #pragma unroll
        for (int i = 0; i < 4; ++i) {
            const int lin = t + i*256;              // 0..1023
            const int r = lin >> 4, kq = lin & 15;
            const float4 v = *(const float4*)(seq + (size_t)(rowbase + r)*FIN + kc*64 + kq*4);
            *(float4*)&xs[r][kq*4] = v;
        }
        #pragma unroll
        for (int i = 0; i < 4; ++i) {
            const int lin = t + i*256;
            const int k = lin >> 4, dq = lin & 15;
            const float4 v = *(const float4*)(W1 + ((size_t)head*FIN + kc*64 + k)*HID + dq*4);
            *(float4*)&U.w[k][dq*4] = v;
        }
        __syncthreads();
        #pragma unroll 8
        for (int k = 0; k < 64; ++k) {
            const float4 bb = *(const float4*)&U.w[k][tc*4];
            #pragma unroll
            for (int i = 0; i < 4; ++i) {
                const float a = xs[tr*4 + i][k];
                acc[i][0] += a * bb.x; acc[i][1] += a * bb.y;
                acc[i][2] += a * bb.z; acc[i][3] += a * bb.w;
            }
        }
        __syncthreads();
    }

    // write fts1 + partial dots for f1/f2
    float p1[4], p2[4];
    #pragma unroll
    for (int i = 0; i < 4; ++i) {
        const int node = rowbase + tr*4 + i;
        float4 o; o.x = acc[i][0]; o.y = acc[i][1]; o.z = acc[i][2]; o.w = acc[i][3];
        *(float4*)&fts1[((size_t)node*NH + head)*HID + tc*4] = o;
        float s1 = 0.f, s2 = 0.f;
        #pragma unroll
        for (int j = 0; j < 4; ++j) {
            s1 += acc[i][j] * a1s[head*HID + tc*4 + j];
            s2 += acc[i][j] * a1d[head*HID + tc*4 + j];
        }
        p1[i] = s1; p2[i] = s2;
    }
    #pragma unroll
    for (int i = 0; i < 4; ++i) {
        U.red.r1[tr*4 + i][tc] = p1[i];
        U.red.r2[tr*4 + i][tc] = p2[i];
    }
    __syncthreads();
    if (t < 64) {
        float s1 = b1s[head], s2 = b1d[head];
        #pragma unroll
        for (int q = 0; q < 16; ++q) { s1 += U.red.r1[t][q]; s2 += U.red.r2[t][q]; }
        const int node = rowbase + t;
        f1v[node*NH + head] = s1;
        f2v[node*NH + head] = s2;
    }
}

// ---------------------------------------------------------------------------
// Kernel B: per-node sparse attention (layer 1, 4 heads = 4 waves), fused with
// elu+bias1, head-concat, fts2 = h1 @ W2, and layer-2 src/dst scalars.
// ---------------------------------------------------------------------------
__global__ __launch_bounds__(256) void k_attn1(
    const float* __restrict__ fts1, const float* __restrict__ f1v,
    const float* __restrict__ f2v, const float* __restrict__ bias1,
    const float* __restrict__ W2, const float* __restrict__ a2s,
    const float* __restrict__ a2d, const float* __restrict__ b2s,
    const float* __restrict__ b2d,
    const int* __restrict__ deg, const int* __restrict__ cols,
    float* __restrict__ fts2, float* __restrict__ g1, float* __restrict__ g2)
{
    __shared__ int   colsS[MAXD];
    __shared__ float coefS[NH][MAXD];
    __shared__ float h1row[NH*HID];
    __shared__ float red[16][17];
    __shared__ float fts2S[NC];

    const int i = blockIdx.x;
    const int t = threadIdx.x, h = t >> 6, lane = t & 63;
    const int d = deg[i];
    for (int e = t; e < MAXD; e += 256) colsS[e] = (e < d) ? cols[(size_t)i*MAXD + e] : 0;
    __syncthreads();

    // scores for up to 128 edges (2 chunks of 64)
    const float f1i = f1v[i*NH + h];
    float sc0 = -1e30f, sc1 = -1e30f;
    if (lane < d)      { const float x = f1i + f2v[colsS[lane]*NH + h];    sc0 = x > 0.f ? x : ALPHA*x; }
    if (lane + 64 < d) { const float x = f1i + f2v[colsS[lane+64]*NH + h]; sc1 = x > 0.f ? x : ALPHA*x; }
    float m = fmaxf(sc0, sc1);
    #pragma unroll
    for (int off = 32; off; off >>= 1) m = fmaxf(m, __shfl_xor(m, off));
    const float p0 = (lane      < d) ? expf(sc0 - m) : 0.f;
    const float p1 = (lane + 64 < d) ? expf(sc1 - m) : 0.f;
    coefS[h][lane] = p0; coefS[h][lane + 64] = p1;
    float sum = p0 + p1;
    #pragma unroll
    for (int off = 32; off; off >>= 1) sum += __shfl_xor(sum, off);
    const float inv = 1.f / sum;

    // PV: lane owns hidden dim; gather neighbor feature vectors (L2-resident)
    float acc = 0.f;
    #pragma unroll 4
    for (int e = 0; e < d; ++e)
        acc += coefS[h][e] * fts1[((size_t)colsS[e]*NH + h)*HID + lane];

    const float v = acc*inv + bias1[h*HID + lane];
    h1row[h*HID + lane] = v > 0.f ? v : expm1f(v);   // elu, then concat layout [h*HID+d]
    __syncthreads();

    // fts2 = h1row @ W2  ([256] x [256,16])
    {
        const int c = t & 15, part = t >> 4;
        float s = 0.f;
        #pragma unroll
        for (int q = 0; q < 16; ++q) s += h1row[part*16 + q] * W2[(part*16 + q)*NC + c];
        red[part][c] = s;
    }
    __syncthreads();
    if (t < NC) {
        float s = 0.f;
        #pragma unroll
        for (int q = 0; q < 16; ++q) s += red[q][t];
        fts2S[t] = s;
        fts2[(size_t)i*NC + t] = s;
    }
    __syncthreads();
    if (t == 0) {
        float s1 = b2s[0], s2 = b2d[0];
        #pragma unroll
        for (int c = 0; c < NC; ++c) { s1 += fts2S[c]*a2s[c]; s2 += fts2S[c]*a2d[c]; }
        g1[i] = s1; g2[i] = s2;
    }
}

// ---------------------------------------------------------------------------
// Kernel C: layer-2 sparse attention, 1 wave per node, 4 nodes per block.
// ---------------------------------------------------------------------------
__global__ __launch_bounds__(256) void k_attn2(
    const float* __restrict__ fts2, const float* __restrict__ g1,
    const float* __restrict__ g2, const float* __restrict__ bias2,
    const int* __restrict__ deg, const int* __restrict__ cols,
    float* __restrict__ out)
{
    __shared__ int   colsS[4][MAXD];
    __shared__ float coefS[4][MAXD];
    const int t = threadIdx.x, w = t >> 6, lane = t & 63;
    const int i = blockIdx.x*4 + w;
    const int d = deg[i];
    for (int e = lane; e < MAXD; e += 64) colsS[w][e] = (e < d) ? cols[(size_t)i*MAXD + e] : 0;

    const float g1i = g1[i];
    float sc0 = -1e30f, sc1 = -1e30f;
    if (lane < d)      { const float x = g1i + g2[colsS[w][lane]];    sc0 = x > 0.f ? x : ALPHA*x; }
    if (lane + 64 < d) { const float x = g1i + g2[colsS[w][lane+64]]; sc1 = x > 0.f ? x : ALPHA*x; }
    float m = fmaxf(sc0, sc1);
    #pragma unroll
    for (int off = 32; off; off >>= 1) m = fmaxf(m, __shfl_xor(m, off));
    const float p0 = (lane      < d) ? expf(sc0 - m) : 0.f;
    const float p1 = (lane + 64 < d) ? expf(sc1 - m) : 0.f;
    coefS[w][lane] = p0; coefS[w][lane + 64] = p1;
    float sum = p0 + p1;
    #pragma unroll
    for (int off = 32; off; off >>= 1) sum += __shfl_xor(sum, off);
    const float inv = 1.f / sum;

    if (lane < NC) {
        float acc = 0.f;
        #pragma unroll 4
        for (int e = 0; e < d; ++e)
            acc += coefS[w][e] * fts2[(size_t)colsS[w][e]*NC + lane];
        out[(size_t)i*NC + lane] = acc*inv + bias2[lane];
    }
}

// ---------------------------------------------------------------------------
extern "C" void kernel_launch(void* const* d_in, const int* in_sizes, int n_in,
                              void* d_out, int out_size, void* d_ws, size_t ws_size,
                              hipStream_t stream)
{
    const float* seq   = (const float*)d_in[0];
    const float* bias  = (const float*)d_in[1];
    const float* W1    = (const float*)d_in[2];
    const float* a1s   = (const float*)d_in[3];
    const float* a1d   = (const float*)d_in[4];
    const float* b1s   = (const float*)d_in[5];
    const float* b1d   = (const float*)d_in[6];
    const float* bias1 = (const float*)d_in[7];
    const float* W2    = (const float*)d_in[8];
    const float* a2s   = (const float*)d_in[9];
    const float* a2d   = (const float*)d_in[10];
    const float* b2s   = (const float*)d_in[11];
    const float* b2d   = (const float*)d_in[12];
    const float* bias2 = (const float*)d_in[13];

    char* ws = (char*)d_ws;
    int*   deg  = (int*)ws;    ws += (size_t)NN * 4;
    int*   cols = (int*)ws;    ws += (size_t)NN * MAXD * 4;
    float* fts1 = (float*)ws;  ws += (size_t)NN * NH * HID * 4;
    float* f1v  = (float*)ws;  ws += (size_t)NN * NH * 4;
    float* f2v  = (float*)ws;  ws += (size_t)NN * NH * 4;
    float* fts2 = (float*)ws;  ws += (size_t)NN * NC * 4;
    float* g1   = (float*)ws;  ws += (size_t)NN * 4;
    float* g2   = (float*)ws;  ws += (size_t)NN * 4;

    hipLaunchKernelGGL(k_scan_gemm, dim3(512 + 2048), dim3(256), 0, stream,
                       bias, seq, W1, a1s, a1d, b1s, b1d, deg, cols, fts1, f1v, f2v);
    hipLaunchKernelGGL(k_attn1, dim3(NN), dim3(256), 0, stream,
                       fts1, f1v, f2v, bias1, W2, a2s, a2d, b2s, b2d, deg, cols,
                       fts2, g1, g2);
    hipLaunchKernelGGL(k_attn2, dim3(NN/4), dim3(256), 0, stream,
                       fts2, g1, g2, bias2, deg, cols, (float*)d_out);
}